// Round 1
// baseline (2357.464 us; speedup 1.0000x reference)
//
#include <hip/hip_runtime.h>
#include <math.h>

namespace {
constexpr int kB  = 128;
constexpr int kD  = 1024;
constexpr int kH1 = 512;
constexpr int kH2 = 256;
constexpr int kChunk = 16;   // batches per V/M scratch chunk (ws use ~37.5 MB)
}

// dst[c*R + r] = src[r*C + c]
__global__ void transpose_kernel(const float* __restrict__ src, float* __restrict__ dst,
                                 int R, int C) {
    __shared__ float tile[32][33];
    int c0 = blockIdx.x * 32, r0 = blockIdx.y * 32;
    int tx = threadIdx.x & 31, ty = threadIdx.x >> 5;  // 256 threads: ty 0..7
    #pragma unroll
    for (int i = ty; i < 32; i += 8)
        tile[i][tx] = src[(size_t)(r0 + i) * C + c0 + tx];
    __syncthreads();
    #pragma unroll
    for (int i = ty; i < 32; i += 8)
        dst[(size_t)(c0 + i) * R + r0 + tx] = tile[tx][i];
}

// c = sigmoid(A[b,:] @ Bt[:,n] + bias[n]); optional second copy + s = c*(1-c)
__global__ void fwd_kernel(const float* __restrict__ A, const float* __restrict__ Bt,
                           const float* __restrict__ bias, int K, int N,
                           float* __restrict__ c_out, float* __restrict__ c2_out,
                           float* __restrict__ s_out) {
    int b = blockIdx.y;
    int n = blockIdx.x * 256 + threadIdx.x;
    if (n >= N) return;
    const float* a = A + (size_t)b * K;
    float acc0 = 0.f, acc1 = 0.f, acc2 = 0.f, acc3 = 0.f;
    #pragma unroll 4
    for (int k = 0; k < K; k += 4) {
        acc0 += a[k + 0] * Bt[(size_t)(k + 0) * N + n];
        acc1 += a[k + 1] * Bt[(size_t)(k + 1) * N + n];
        acc2 += a[k + 2] * Bt[(size_t)(k + 2) * N + n];
        acc3 += a[k + 3] * Bt[(size_t)(k + 3) * N + n];
    }
    float v = (acc0 + acc1) + (acc2 + acc3) + bias[n];
    float c = 1.0f / (1.0f + expf(-v));
    c_out[(size_t)b * N + n] = c;
    if (c2_out) c2_out[(size_t)b * N + n] = c;
    if (s_out)  s_out[(size_t)b * N + n] = c * (1.0f - c);
}

// For each local batch bl (global b = b0+bl):
//   V[f,d] = sum_h W2[f,h]*s1[b,h]*W1[h,d]
//   M[f,d] = s2[b,f] * sum_h W2[f,h]*s3[b,h]*W1[h,d]
// grid: (kD/64, kH2/64, kChunk), block 256, 4x4 per-thread blocking, shared B-tile.
__global__ __launch_bounds__(256) void vm_kernel(
    const float* __restrict__ W1, const float* __restrict__ W2,
    const float* __restrict__ s1, const float* __restrict__ s2,
    const float* __restrict__ s3,
    float* __restrict__ V, float* __restrict__ M, int b0) {
    __shared__ float Av[32][64];
    __shared__ float Am[32][64];
    __shared__ float Bs[32][64];
    const int bl = blockIdx.z;
    const int b  = b0 + bl;
    const int f0 = blockIdx.y * 64;
    const int d0 = blockIdx.x * 64;
    const int tid = threadIdx.x;
    const int tx = tid & 15, ty = tid >> 4;
    float accv[4][4] = {{0.f}};
    float accm[4][4] = {{0.f}};
    for (int h0 = 0; h0 < kH1; h0 += 32) {
        {   // A tiles: load W2 [64f x 32h] rows (coalesced along h), scale, store transposed
            const int fl0 = tid >> 3;        // 0..31
            const int hl  = (tid & 7) * 4;   // 0..28
            float4 sv1 = *(const float4*)&s1[(size_t)b * kH1 + h0 + hl];
            float4 sv3 = *(const float4*)&s3[(size_t)b * kH1 + h0 + hl];
            #pragma unroll
            for (int p = 0; p < 2; p++) {
                int fl = fl0 + p * 32;
                float4 w = *(const float4*)&W2[(size_t)(f0 + fl) * kH1 + h0 + hl];
                Av[hl + 0][fl] = w.x * sv1.x;  Am[hl + 0][fl] = w.x * sv3.x;
                Av[hl + 1][fl] = w.y * sv1.y;  Am[hl + 1][fl] = w.y * sv3.y;
                Av[hl + 2][fl] = w.z * sv1.z;  Am[hl + 2][fl] = w.z * sv3.z;
                Av[hl + 3][fl] = w.w * sv1.w;  Am[hl + 3][fl] = w.w * sv3.w;
            }
        }
        {   // B tile: W1 [32h x 64d], direct
            const int hl0 = tid >> 4;        // 0..15
            const int dl  = (tid & 15) * 4;
            #pragma unroll
            for (int p = 0; p < 2; p++) {
                int hl = hl0 + p * 16;
                *(float4*)&Bs[hl][dl] = *(const float4*)&W1[(size_t)(h0 + hl) * kD + d0 + dl];
            }
        }
        __syncthreads();
        #pragma unroll
        for (int kk = 0; kk < 32; kk++) {
            float4 av = *(float4*)&Av[kk][ty * 4];
            float4 am = *(float4*)&Am[kk][ty * 4];
            float4 bv = *(float4*)&Bs[kk][tx * 4];
            float a[4]  = {av.x, av.y, av.z, av.w};
            float m[4]  = {am.x, am.y, am.z, am.w};
            float bb[4] = {bv.x, bv.y, bv.z, bv.w};
            #pragma unroll
            for (int i = 0; i < 4; i++)
                #pragma unroll
                for (int j = 0; j < 4; j++) {
                    accv[i][j] += a[i] * bb[j];
                    accm[i][j] += m[i] * bb[j];
                }
        }
        __syncthreads();
    }
    #pragma unroll
    for (int i = 0; i < 4; i++) {
        int f = f0 + ty * 4 + i;
        float s2v = s2[(size_t)b * kH2 + f];
        float4 vv = make_float4(accv[i][0], accv[i][1], accv[i][2], accv[i][3]);
        float4 mm = make_float4(accm[i][0] * s2v, accm[i][1] * s2v,
                                accm[i][2] * s2v, accm[i][3] * s2v);
        *(float4*)&V[((size_t)(bl * kH2 + f)) * kD + d0 + tx * 4] = vv;
        *(float4*)&M[((size_t)(bl * kH2 + f)) * kD + d0 + tx * 4] = mm;
    }
}

// Jst_b[d,e] = sum_f V_b[f,d] * M_b[f,e]; write permuted:
//   jac[((d>>3)*1024 + (d&7)*128 + b)*1024 + e]
// grid: (kD/64 e-tiles, kD/128 d-tiles, kChunk), block 256, 8x4 per-thread.
__global__ __launch_bounds__(256) void jac_kernel(
    const float* __restrict__ V, const float* __restrict__ M,
    float* __restrict__ jac, int b0) {
    __shared__ float Vt[32][128];
    __shared__ float Mt[32][64];
    const int bl = blockIdx.z;
    const int b  = b0 + bl;
    const int d0 = blockIdx.y * 128;
    const int e0 = blockIdx.x * 64;
    const int tid = threadIdx.x;
    const int tx = tid & 15, ty = tid >> 4;
    const float* Vb = V + (size_t)bl * kH2 * kD;
    const float* Mb = M + (size_t)bl * kH2 * kD;
    float acc[8][4] = {{0.f}};
    for (int f0v = 0; f0v < kH2; f0v += 32) {
        {   // Vt[kk][d'] = V[f0v+kk][d0+d'], 32x128 direct (coalesced)
            const int fl0 = tid >> 5;        // 0..7
            const int dl  = (tid & 31) * 4;  // 0..124
            #pragma unroll
            for (int p = 0; p < 4; p++) {
                int fl = fl0 + p * 8;
                *(float4*)&Vt[fl][dl] = *(const float4*)&Vb[(size_t)(f0v + fl) * kD + d0 + dl];
            }
        }
        {   // Mt[kk][e'] = M[f0v+kk][e0+e'], 32x64 direct
            const int fl0 = tid >> 4;        // 0..15
            const int el  = (tid & 15) * 4;
            #pragma unroll
            for (int p = 0; p < 2; p++) {
                int fl = fl0 + p * 16;
                *(float4*)&Mt[fl][el] = *(const float4*)&Mb[(size_t)(f0v + fl) * kD + e0 + el];
            }
        }
        __syncthreads();
        #pragma unroll
        for (int kk = 0; kk < 32; kk++) {
            float4 v0 = *(float4*)&Vt[kk][ty * 8];
            float4 v1 = *(float4*)&Vt[kk][ty * 8 + 4];
            float4 mv = *(float4*)&Mt[kk][tx * 4];
            float a[8] = {v0.x, v0.y, v0.z, v0.w, v1.x, v1.y, v1.z, v1.w};
            float c[4] = {mv.x, mv.y, mv.z, mv.w};
            #pragma unroll
            for (int i = 0; i < 8; i++)
                #pragma unroll
                for (int j = 0; j < 4; j++)
                    acc[i][j] += a[i] * c[j];
        }
        __syncthreads();
    }
    #pragma unroll
    for (int i = 0; i < 8; i++) {
        int d = d0 + ty * 8 + i;
        int row = ((d >> 3) << 10) + ((d & 7) << 7) + b;
        *(float4*)&jac[(size_t)row * kD + e0 + tx * 4] =
            make_float4(acc[i][0], acc[i][1], acc[i][2], acc[i][3]);
    }
}

extern "C" void kernel_launch(void* const* d_in, const int* in_sizes, int n_in,
                              void* d_out, int out_size, void* d_ws, size_t ws_size,
                              hipStream_t stream) {
    const float* x  = (const float*)d_in[0];   // [128,1024]
    const float* W1 = (const float*)d_in[1];   // [512,1024]
    const float* b1 = (const float*)d_in[2];   // [512]
    const float* W2 = (const float*)d_in[3];   // [256,512]
    const float* b2 = (const float*)d_in[4];   // [256]
    const float* b3 = (const float*)d_in[5];   // [512]
    const float* br = (const float*)d_in[6];   // [1024]
    float* out = (float*)d_out;
    float* ws  = (float*)d_ws;

    // workspace layout (floats)
    float* W1t = ws;                         // 1024*512 = 524288
    float* W2t = W1t + 524288;               // 512*256  = 131072
    float* c1  = W2t + 131072;               // 65536
    float* s1  = c1  + 65536;                // 65536
    float* c2  = s1  + 65536;                // 32768
    float* s2  = c2  + 32768;                // 32768
    float* c3  = s2  + 32768;                // 65536
    float* s3  = c3  + 65536;                // 65536
    float* V   = s3  + 65536;                // kChunk*256*1024
    float* M   = V + (size_t)kChunk * kH2 * kD;

    float* recover = out;                        // [128,1024]
    float* c2_out  = out + kB * kD;              // [128,256]
    float* jac     = out + kB * kD + kB * kH2;   // [128,1024,1024] (permuted rows)

    transpose_kernel<<<dim3(kD / 32, kH1 / 32), 256, 0, stream>>>(W1, W1t, kH1, kD);
    transpose_kernel<<<dim3(kH1 / 32, kH2 / 32), 256, 0, stream>>>(W2, W2t, kH2, kH1);

    // c1 = sig(x @ W1^T + b1)      : A=x,  Bt=W1t [1024,512]
    fwd_kernel<<<dim3((kH1 + 255) / 256, kB), 256, 0, stream>>>(x,  W1t, b1, kD,  kH1, c1, nullptr, s1);
    // c2 = sig(c1 @ W2^T + b2)     : Bt=W2t [512,256]; also write to d_out
    fwd_kernel<<<dim3((kH2 + 255) / 256, kB), 256, 0, stream>>>(c1, W2t, b2, kH1, kH2, c2, c2_out, s2);
    // c3 = sig(c2 @ W2 + b3)       : Bt=W2 as-is [256,512]
    fwd_kernel<<<dim3((kH1 + 255) / 256, kB), 256, 0, stream>>>(c2, W2,  b3, kH2, kH1, c3, nullptr, s3);
    // recover = sig(c3 @ W1 + b_r) : Bt=W1 as-is [512,1024]
    fwd_kernel<<<dim3((kD  + 255) / 256, kB), 256, 0, stream>>>(c3, W1,  br, kH1, kD,  recover, nullptr, nullptr);

    for (int b0 = 0; b0 < kB; b0 += kChunk) {
        vm_kernel<<<dim3(kD / 64, kH2 / 64, kChunk), 256, 0, stream>>>(W1, W2, s1, s2, s3, V, M, b0);
        jac_kernel<<<dim3(kD / 64, kD / 128, kChunk), 256, 0, stream>>>(V, M, jac, b0);
    }
}